// Round 13
// baseline (154.124 us; speedup 1.0000x reference)
//
#include <hip/hip_runtime.h>
#include <stdint.h>

// Problem constants (fixed by setup_inputs: N=8192, D=8, fp32).
constexpr int N = 8192;
constexpr int BLK = 256;           // threads per block (4 waves)
constexpr int NCH = N / BLK;       // 32 row-chunks per matrix
constexpr int JSPLIT_R = 8;        // rank kernel j-splits
constexpr int JSEG_R = N / JSPLIT_R;

typedef float f32x4 __attribute__((ext_vector_type(4)));
typedef uint32_t u32x16 __attribute__((ext_vector_type(16)));
typedef uint64_t u64x8 __attribute__((ext_vector_type(8)));

// j-rows / keys through the SCALAR path: one s_load_dwordx16 = 64 B.
#define SLOAD16(dst, base, immstr) \
  asm volatile("s_load_dwordx16 %0, %1, " immstr : "=s"(dst) : "s"(base))

// One j-row vs 64 i-rows: EXACT 14 VALU, written as asm so no compiler glue
// (R12 measured ~26/row: SGPR->VGPR movs + cndmask crept in).
// Strict dominance i-over-j: max_d(M[j,d] - M[i,d]) < 0; ties/self -> >=0 ->
// rejected (semantics validated absmax 0.0 across R1-R12).
#define JROW8(q, e)                                                          \
  {                                                                          \
    float t0, t1, t2, t3, t4, t5, t6, t7;                                    \
    asm volatile(                                                            \
        "v_sub_f32 %[t0], %[a0], %[x0]\n\t"                                  \
        "v_sub_f32 %[t1], %[a1], %[x1]\n\t"                                  \
        "v_sub_f32 %[t2], %[a2], %[x2]\n\t"                                  \
        "v_sub_f32 %[t3], %[a3], %[x3]\n\t"                                  \
        "v_sub_f32 %[t4], %[a4], %[x4]\n\t"                                  \
        "v_sub_f32 %[t5], %[a5], %[x5]\n\t"                                  \
        "v_sub_f32 %[t6], %[a6], %[x6]\n\t"                                  \
        "v_sub_f32 %[t7], %[a7], %[x7]\n\t"                                  \
        "v_max3_f32 %[t0], %[t0], %[t1], %[t2]\n\t"                          \
        "v_max3_f32 %[t3], %[t3], %[t4], %[t5]\n\t"                          \
        "v_max3_f32 %[t6], %[t6], %[t7], %[t0]\n\t"                          \
        "v_max_f32 %[t3], %[t3], %[t6]\n\t"                                  \
        "v_cmp_gt_f32 vcc, 0, %[t3]\n\t"                                     \
        "v_addc_co_u32 %[c], vcc, 0, %[c], vcc"                              \
        : [c] "+v"(cnt), [t0] "=&v"(t0), [t1] "=&v"(t1), [t2] "=&v"(t2),     \
          [t3] "=&v"(t3), [t4] "=&v"(t4), [t5] "=&v"(t5), [t6] "=&v"(t6),    \
          [t7] "=&v"(t7)                                                     \
        : [a0] "s"(q[e + 0]), [a1] "s"(q[e + 1]), [a2] "s"(q[e + 2]),        \
          [a3] "s"(q[e + 3]), [a4] "s"(q[e + 4]), [a5] "s"(q[e + 5]),        \
          [a6] "s"(q[e + 6]), [a7] "s"(q[e + 7]), [x0] "v"(xi0),             \
          [x1] "v"(xi1), [x2] "v"(xi2), [x3] "v"(xi3), [x4] "v"(xi4),        \
          [x5] "v"(xi5), [x6] "v"(xi6), [x7] "v"(xi7)                        \
        : "vcc");                                                            \
  }

// 64-bit (sortable-d0, index) key compare: 2 VALU per 64 pairs.
#define KEYCMP(kj)                                      \
  asm volatile(                                         \
      "v_cmp_lt_u64 vcc, %[a], %[b]\n\t"                \
      "v_addc_co_u32 %[c], vcc, 0, %[c], vcc"           \
      : [c] "+v"(cnt)                                   \
      : [a] "s"(kj), [b] "v"(ki)                        \
      : "vcc");

// f32 -> order-preserving u32; key = (u << 13) | row-index (strict total
// order even under d0 ties -> rank is always a permutation).
__device__ __forceinline__ uint64_t sortkey(float f, int idx) {
  uint32_t b = __float_as_uint(f);
  uint32_t m = (uint32_t)((int32_t)b >> 31);
  uint32_t s = b ^ (m | 0x80000000u);
  return ((uint64_t)s << 13) | (uint32_t)idx;
}

// ---- sort pipeline (counts are permutation-invariant: the histogram only
// consumes the multiset, so we may reorder rows freely). Sorting by d0 makes
// dominance impossible for j above i -> skip the upper triangle (2x work cut).

__global__ __launch_bounds__(BLK) void key_kernel(
    const float* __restrict__ X, const float* __restrict__ Xh,
    uint64_t* __restrict__ keys) {
  const int r = blockIdx.x * BLK + threadIdx.x;  // [0, 2N)
  const int m = r >> 13, i = r & (N - 1);
  const float d0 = (m ? Xh : X)[(size_t)i * 8];
  keys[r] = sortkey(d0, i);
}

// rank[r] = #{ j in same matrix : key_j < key_r }  (exact permutation 0..N-1)
__global__ __launch_bounds__(BLK, 8) void rank_kernel(
    const uint64_t* __restrict__ keys, int* __restrict__ rank) {
  const int m = blockIdx.z;
  const uint64_t* __restrict__ K = keys + (size_t)m * N;
  const int i = blockIdx.x * BLK + threadIdx.x;
  const uint64_t ki = K[i];
  int cnt = 0;
  const uint64_t* jb = K + (size_t)blockIdx.y * JSEG_R;
  for (int jj = 0; jj < JSEG_R; jj += 8) {
    u64x8 q;
    SLOAD16(q, jb + jj, "0x0");
    asm volatile("s_waitcnt lgkmcnt(0)" : "+s"(q));  // R11-proven anti-hoist
    KEYCMP(q[0]) KEYCMP(q[1]) KEYCMP(q[2]) KEYCMP(q[3])
    KEYCMP(q[4]) KEYCMP(q[5]) KEYCMP(q[6]) KEYCMP(q[7])
  }
  atomicAdd(&rank[(size_t)m * N + i], cnt);
}

__global__ __launch_bounds__(BLK) void scatter_kernel(
    const float* __restrict__ X, const float* __restrict__ Xh,
    const int* __restrict__ rank, float* __restrict__ Xs) {
  const int r = blockIdx.x * BLK + threadIdx.x;  // [0, 2N)
  const int m = r >> 13, i = r & (N - 1);
  const f32x4* src = reinterpret_cast<const f32x4*>((m ? Xh : X) + (size_t)i * 8);
  f32x4* dst = reinterpret_cast<f32x4*>(Xs + (size_t)m * N * 8 +
                                        (size_t)rank[r] * 8);
  dst[0] = src[0];
  dst[1] = src[1];
}

// ---- triangular dominance counts on d0-sorted rows ----
// Block (ib, jc, m), jc <= ib only. Full 8-dim check everywhere (diagonal and
// ties handled exactly; the skipped upper triangle is provably zero: j above i
// has d0_j >= d0_i so strict d0 dominance fails).
__global__ __launch_bounds__(BLK, 8) void dom_count_kernel(
    const float* __restrict__ Xs, int* __restrict__ counts) {
  const int ib = blockIdx.x, jc = blockIdx.y, m = blockIdx.z;
  if (jc > ib) return;
  const float* __restrict__ M = Xs + (size_t)m * N * 8;
  int* cnt_out = counts + (size_t)m * N;

  const int i = ib * BLK + threadIdx.x;
  const f32x4* Mi = reinterpret_cast<const f32x4*>(M + (size_t)i * 8);
  const f32x4 ra = Mi[0];
  const f32x4 rb = Mi[1];
  const float xi0 = ra.x, xi1 = ra.y, xi2 = ra.z, xi3 = ra.w;
  const float xi4 = rb.x, xi5 = rb.y, xi6 = rb.z, xi7 = rb.w;

  int cnt = 0;
  const float* jb = M + (size_t)(jc * BLK) * 8;
  for (int jj = 0; jj < BLK; jj += 8) {
    u32x16 q0, q1, q2, q3;
    const float* gb = jb + (size_t)jj * 8;
    SLOAD16(q0, gb, "0x0");
    SLOAD16(q1, gb, "0x40");
    SLOAD16(q2, gb, "0x80");
    SLOAD16(q3, gb, "0xC0");
    asm volatile("s_waitcnt lgkmcnt(0)"
                 : "+s"(q0), "+s"(q1), "+s"(q2), "+s"(q3));
    JROW8(q0, 0) JROW8(q0, 8)
    JROW8(q1, 0) JROW8(q1, 8)
    JROW8(q2, 0) JROW8(q2, 8)
    JROW8(q3, 0) JROW8(q3, 8)
  }
  atomicAdd(&cnt_out[i], cnt);
}

// ---- fallback flat dominance (R12 structure, asm body) for small ws ----
__global__ __launch_bounds__(BLK, 8) void dom_flat_kernel(
    const float* __restrict__ X, const float* __restrict__ Xh,
    int* __restrict__ counts) {
  const float* __restrict__ M = (blockIdx.z == 0) ? X : Xh;
  int* cnt_out = counts + (size_t)blockIdx.z * N;
  const int i = blockIdx.x * BLK + threadIdx.x;
  const f32x4* Mi = reinterpret_cast<const f32x4*>(M + (size_t)i * 8);
  const f32x4 ra = Mi[0];
  const f32x4 rb = Mi[1];
  const float xi0 = ra.x, xi1 = ra.y, xi2 = ra.z, xi3 = ra.w;
  const float xi4 = rb.x, xi5 = rb.y, xi6 = rb.z, xi7 = rb.w;
  int cnt = 0;
  const float* jb = M + (size_t)(blockIdx.y * BLK) * 8;
  for (int jj = 0; jj < BLK; jj += 8) {
    u32x16 q0, q1, q2, q3;
    const float* gb = jb + (size_t)jj * 8;
    SLOAD16(q0, gb, "0x0");
    SLOAD16(q1, gb, "0x40");
    SLOAD16(q2, gb, "0x80");
    SLOAD16(q3, gb, "0xC0");
    asm volatile("s_waitcnt lgkmcnt(0)"
                 : "+s"(q0), "+s"(q1), "+s"(q2), "+s"(q3));
    JROW8(q0, 0) JROW8(q0, 8)
    JROW8(q1, 0) JROW8(q1, 8)
    JROW8(q2, 0) JROW8(q2, 8)
    JROW8(q3, 0) JROW8(q3, 8)
  }
  atomicAdd(&cnt_out[i], cnt);
}

// --- Finalize, stage 1: privatized histograms (R3-proven) -------------------
// sum_k |sort(a)_k - sort(b)_k| == sum_t |#{a<=t} - #{b<=t}|; histogram +1 for
// X counts, -1 for Xh counts. 16 blocks privatize hot-bin contention.
constexpr int HB = 16;
__global__ __launch_bounds__(1024) void hist_partial_kernel(
    const int* __restrict__ counts, int* __restrict__ ghist) {
  __shared__ int lhist[N];  // 32 KB
  const int tid = threadIdx.x;
  for (int q = tid; q < N; q += 1024) lhist[q] = 0;
  __syncthreads();

  const int k = blockIdx.x * (2 * N / HB) + tid;  // 1024 values per block
  const int v = counts[k];
  atomicAdd(&lhist[v], (k < N) ? 1 : -1);
  __syncthreads();

#pragma unroll
  for (int q = 0; q < N / 1024; ++q) {
    const int bin = tid * (N / 1024) + q;
    const int h = lhist[bin];
    if (h != 0) atomicAdd(&ghist[bin], h);
  }
}

// --- Finalize, stage 2: scan + abs-sum (one small block, R3-proven) ---------
__global__ __launch_bounds__(1024) void finalize_kernel(
    const int* __restrict__ ghist, float* __restrict__ out) {
  __shared__ int wsum[16];
  __shared__ int wexc[16];
  __shared__ int wabs[16];

  const int tid = threadIdx.x;
  const int lane = tid & 63;
  const int wid = tid >> 6;

  int local[8];
  int s = 0;
#pragma unroll
  for (int q = 0; q < 8; ++q) {
    local[q] = ghist[tid * 8 + q];
    s += local[q];
  }

  int incl = s;  // wave-inclusive scan of per-thread sums
#pragma unroll
  for (int off = 1; off < 64; off <<= 1) {
    const int v = __shfl_up(incl, off);
    if (lane >= off) incl += v;
  }
  if (lane == 63) wsum[wid] = incl;
  __syncthreads();

  if (tid == 0) {
    int acc = 0;
#pragma unroll
    for (int w = 0; w < 16; ++w) { wexc[w] = acc; acc += wsum[w]; }
  }
  __syncthreads();

  int run = wexc[wid] + (incl - s);  // exclusive prefix of my 8-bin chunk
  int acc = 0;
#pragma unroll
  for (int q = 0; q < 8; ++q) {
    run += local[q];
    acc += (run < 0) ? -run : run;
  }

#pragma unroll
  for (int off = 32; off > 0; off >>= 1) acc += __shfl_down(acc, off);
  if (lane == 0) wabs[wid] = acc;
  __syncthreads();

  if (tid == 0) {
    int total = 0;
#pragma unroll
    for (int w = 0; w < 16; ++w) total += wabs[w];
    // result = total / (N-1) / N
    out[0] = (float)((double)total / ((double)(N - 1) * (double)N));
  }
}

extern "C" void kernel_launch(void* const* d_in, const int* in_sizes, int n_in,
                              void* d_out, int out_size, void* d_ws, size_t ws_size,
                              hipStream_t stream) {
  const float* X = (const float*)d_in[0];
  const float* Xh = (const float*)d_in[1];
  float* out = (float*)d_out;

  // ws layout: [counts 2N int][ghist N int][rank 2N int][keys 2N u64][Xs 16N f32]
  int* counts = (int*)d_ws;
  int* ghist = counts + 2 * N;
  int* rank = counts + 3 * N;
  uint64_t* keys = (uint64_t*)(counts + 5 * N);
  float* Xs = (float*)(keys + 2 * N);
  const size_t needed = (size_t)5 * N * 4 + (size_t)2 * N * 8 + (size_t)16 * N * 4;

  if (ws_size >= needed) {
    hipMemsetAsync(counts, 0, (size_t)5 * N * sizeof(int), stream);
    key_kernel<<<2 * N / BLK, BLK, 0, stream>>>(X, Xh, keys);
    rank_kernel<<<dim3(NCH, JSPLIT_R, 2), BLK, 0, stream>>>(keys, rank);
    scatter_kernel<<<2 * N / BLK, BLK, 0, stream>>>(X, Xh, rank, Xs);
    dom_count_kernel<<<dim3(NCH, NCH, 2), BLK, 0, stream>>>(Xs, counts);
  } else {
    hipMemsetAsync(counts, 0, (size_t)3 * N * sizeof(int), stream);
    dom_flat_kernel<<<dim3(NCH, NCH, 2), BLK, 0, stream>>>(X, Xh, counts);
  }
  hist_partial_kernel<<<HB, 1024, 0, stream>>>(counts, ghist);
  finalize_kernel<<<1, 1024, 0, stream>>>(ghist, out);
}